// Round 13
// baseline (94.759 us; speedup 1.0000x reference)
//
#include <hip/hip_runtime.h>

// HungarianMatcher batched cost matrix. B=64, Q=900, T=300, C=80.
// cost = 5*cbbox + (2*ccls + 2) - 2*(inter*ca + uni^2)/(uni*ca)
//
// R13: occupancy play. Waves/CU halve at VGPR=64/128/256 (m69); R12's
// unbounded NQ=9 unroll sits in the 65-128 class -> 16 waves/CU. This
// version is engineered into the <=64-VGPR class: BLOCK=256 with
// launch_bounds(256,8) (the clean "k blocks/CU" case: 8 blocks/CU, cap
// 64), persistent state trimmed to ~26 regs: targets as xyxy ONLY (16),
// cbbox from corner diffs (|dcx|=0.5|dx0+dx1|, |dw|=|dx1-dx0|), tw/ta
// derived per elem, s_pA GONE (pw/ph/pa derive from pB) -> 1 broadcast
// per q-iter. QTILE=12, tq=tid/75 (225 active), NQ=4, grid 4800.
// R10's lesson: spill shows as FETCH/WRITE blowup -> revert if seen.

constexpr int B = 64, Q = 900, T = 300, C = 80;
constexpr int QTILE = 12;            // 75 q-tiles -> grid 4800
constexpr int BLOCK = 256;           // 4 waves; 225 active in main
constexpr int NTQ   = 3;             // q sub-lanes
constexpr int NQ    = QTILE / NTQ;   // 4 q per thread
constexpr float ALPHA = 0.25f;

__device__ __forceinline__ float fast_rcp(float x) {
    return __builtin_amdgcn_rcpf(x);
}

// 2*(pos-neg)+2 with one exp, one rcp, one log.
__device__ __forceinline__ float focal2(float x) {
    float t  = __expf(-x);
    float p  = fast_rcp(1.0f + t);
    float L  = __logf(1.0f + t);      // = -log(p)
    float xL = x + L;                 // = -log(1-p)
    float omp = t * p;                // 1-p
    float pos = ALPHA * omp * omp * L;
    float neg = (1.0f - ALPHA) * p * p * xL;
    return fmaf(2.0f, pos - neg, 2.0f);
}

__global__ __launch_bounds__(BLOCK, 8) void matcher_cost_kernel(
    const float* __restrict__ logits,    // [B,Q,C]
    const float* __restrict__ pboxes,    // [B,Q,4] cxcywh
    const int*   __restrict__ tlabels,   // [B,T]
    const float* __restrict__ tboxes,    // [B,T,4] cxcywh
    float* __restrict__ out)             // [B,Q,T]
{
    __shared__ float  s_cls[QTILE * C];  // 3.84 KB
    __shared__ float4 s_pB[QTILE];       // x0,y0,x1,y1 (192 B)

    const int bid = blockIdx.x;
    const int b   = bid / (Q / QTILE);
    const int q0  = (bid % (Q / QTILE)) * QTILE;
    const int tid = threadIdx.x;

    // ---- pred boxes (xyxy only) ----
    if (tid < QTILE) {
        float4 bx = *(const float4*)(pboxes + ((size_t)b * Q + q0 + tid) * 4);
        s_pB[tid] = make_float4(bx.x - 0.5f * bx.z, bx.y - 0.5f * bx.w,
                                bx.x + 0.5f * bx.z, bx.y + 0.5f * bx.w);
    }
    // ---- focal class table: 960 entries ----
    {
        const float* lg = logits + ((size_t)b * Q + q0) * C;
        for (int i = tid; i < QTILE * C; i += BLOCK)
            s_cls[i] = focal2(lg[i]);
    }

    // ---- this thread's 4 targets: global -> registers (xyxy + label) ----
    const int tq = tid / 75;             // 0..2 active
    const int tt = tid - tq * 75;
    const bool active = (tid < NTQ * 75);

    float Tx0[4], Ty0[4], Tx1[4], Ty1[4];
    int lab[4] = {0, 0, 0, 0};
    if (active) {
        const float4* tbp = (const float4*)(tboxes + ((size_t)b * T + tt * 4) * 4);
        int4 lb = *(const int4*)(tlabels + (size_t)b * T + tt * 4);
        lab[0] = lb.x; lab[1] = lb.y; lab[2] = lb.z; lab[3] = lb.w;
        #pragma unroll
        for (int k = 0; k < 4; ++k) {
            float4 bx = tbp[k];
            Tx0[k] = bx.x - 0.5f * bx.z; Ty0[k] = bx.y - 0.5f * bx.w;
            Tx1[k] = bx.x + 0.5f * bx.z; Ty1[k] = bx.y + 0.5f * bx.w;
        }
    }

    __syncthreads();

    if (!active) return;

    const float* cls0 = s_cls + tq * C;  // + j*NTQ*C as imm offsets
    float* op = out + ((size_t)b * Q + q0 + tq) * T + tt * 4;

    #pragma unroll
    for (int j = 0; j < NQ; ++j) {
        float4 pB = s_pB[tq + NTQ * j];  // broadcast b128 (<=3 addrs/wave)
        float pw = pB.z - pB.x, ph = pB.w - pB.y;
        float pa = pw * ph;
        const float* clsj = cls0 + j * NTQ * C;

        float cls_k[4] = { clsj[lab[0]], clsj[lab[1]], clsj[lab[2]], clsj[lab[3]] };

        float4 res;
        #pragma unroll
        for (int k = 0; k < 4; ++k) {
            float dx0 = pB.x - Tx0[k], dx1 = pB.z - Tx1[k];
            float dy0 = pB.y - Ty0[k], dy1 = pB.w - Ty1[k];

            float tw = Tx1[k] - Tx0[k], th = Ty1[k] - Ty0[k];
            float ta = tw * th;

            float wi = fminf(pB.z, Tx1[k]) - fmaxf(pB.x, Tx0[k]);
            float hi = fminf(pB.w, Ty1[k]) - fmaxf(pB.y, Ty0[k]);
            float iw = fmaxf(wi, 0.0f), ih = fmaxf(hi, 0.0f);
            float inter = iw * ih;
            float uni = (pa + ta) - inter;
            float cw  = (pw + tw) - wi;      // max+min identity
            float ch  = (ph + th) - hi;
            float ca  = cw * ch;

            // cbbox from corner diffs: |dcx|=0.5|dx0+dx1|, |dw|=|dx1-dx0|
            float cb = fabsf(dx1 - dx0) + fabsf(dy1 - dy0);
            cb = fmaf(0.5f, fabsf(dx0 + dx1), cb);
            cb = fmaf(0.5f, fabsf(dy0 + dy1), cb);

            float num = fmaf(uni, uni, inter * ca);
            float r   = fast_rcp(uni * ca);
            float c   = fmaf(5.0f, cb, cls_k[k]);
            c = fmaf(num * r, -2.0f, c);

            if (c != c) c = 1.0f;            // nan_to_num; clamp provably no-op

            (&res.x)[k] = c;
        }
        *(float4*)(op + (size_t)(NTQ * j) * T) = res;   // coalesced 16B
    }
}

extern "C" void kernel_launch(void* const* d_in, const int* in_sizes, int n_in,
                              void* d_out, int out_size, void* d_ws, size_t ws_size,
                              hipStream_t stream) {
    const float* logits  = (const float*)d_in[0];  // [B,Q,C]
    const float* pboxes  = (const float*)d_in[1];  // [B,Q,4]
    const int*   tlabels = (const int*)  d_in[2];  // [B,T]
    const float* tboxes  = (const float*)d_in[3];  // [B,T,4]
    float* out = (float*)d_out;                    // [B,Q,T]

    dim3 grid(B * (Q / QTILE));   // 4800 blocks
    dim3 block(BLOCK);
    matcher_cost_kernel<<<grid, block, 0, stream>>>(logits, pboxes, tlabels, tboxes, out);
}

// Round 14
// 32.140 us; speedup vs baseline: 2.9483x; 2.9483x over previous
//
#include <hip/hip_runtime.h>

// HungarianMatcher batched cost matrix. B=64, Q=900, T=300, C=80.
// cost = 5*cbbox + (2*ccls + 2) - 2*(inter*ca + uni^2)/(uni*ca)
//
// R14 = R13 WITHOUT the min-waves launch_bounds clause. Twice now
// (R10: (320,8)->VGPR32, R13: (256,8)->VGPR32) the min-waves clause
// forced the allocator below the working set -> scratch spill (FETCH
// 154MB / WRITE 277MB) and 3x regression DESPITE 75%+ occupancy.
// The structural content is unchanged and still untested: persistent
// set ~26 regs (targets xyxy only; cbbox from corner diffs; s_pA gone,
// pw/ph/pa derived from pB; 1 broadcast per q-iter). Let the allocator
// land naturally in the <=64-VGPR class for 8 blocks/CU.

constexpr int B = 64, Q = 900, T = 300, C = 80;
constexpr int QTILE = 12;            // 75 q-tiles -> grid 4800
constexpr int BLOCK = 256;           // 4 waves; 225 active in main
constexpr int NTQ   = 3;             // q sub-lanes
constexpr int NQ    = QTILE / NTQ;   // 4 q per thread
constexpr float ALPHA = 0.25f;

__device__ __forceinline__ float fast_rcp(float x) {
    return __builtin_amdgcn_rcpf(x);
}

// 2*(pos-neg)+2 with one exp, one rcp, one log.
__device__ __forceinline__ float focal2(float x) {
    float t  = __expf(-x);
    float p  = fast_rcp(1.0f + t);
    float L  = __logf(1.0f + t);      // = -log(p)
    float xL = x + L;                 // = -log(1-p)
    float omp = t * p;                // 1-p
    float pos = ALPHA * omp * omp * L;
    float neg = (1.0f - ALPHA) * p * p * xL;
    return fmaf(2.0f, pos - neg, 2.0f);
}

__global__ __launch_bounds__(BLOCK) void matcher_cost_kernel(
    const float* __restrict__ logits,    // [B,Q,C]
    const float* __restrict__ pboxes,    // [B,Q,4] cxcywh
    const int*   __restrict__ tlabels,   // [B,T]
    const float* __restrict__ tboxes,    // [B,T,4] cxcywh
    float* __restrict__ out)             // [B,Q,T]
{
    __shared__ float  s_cls[QTILE * C];  // 3.84 KB
    __shared__ float4 s_pB[QTILE];       // x0,y0,x1,y1 (192 B)

    const int bid = blockIdx.x;
    const int b   = bid / (Q / QTILE);
    const int q0  = (bid % (Q / QTILE)) * QTILE;
    const int tid = threadIdx.x;

    // ---- pred boxes (xyxy only) ----
    if (tid < QTILE) {
        float4 bx = *(const float4*)(pboxes + ((size_t)b * Q + q0 + tid) * 4);
        s_pB[tid] = make_float4(bx.x - 0.5f * bx.z, bx.y - 0.5f * bx.w,
                                bx.x + 0.5f * bx.z, bx.y + 0.5f * bx.w);
    }
    // ---- focal class table: 960 entries ----
    {
        const float* lg = logits + ((size_t)b * Q + q0) * C;
        for (int i = tid; i < QTILE * C; i += BLOCK)
            s_cls[i] = focal2(lg[i]);
    }

    // ---- this thread's 4 targets: global -> registers (xyxy + label) ----
    const int tq = tid / 75;             // 0..2 active
    const int tt = tid - tq * 75;
    const bool active = (tid < NTQ * 75);

    float Tx0[4], Ty0[4], Tx1[4], Ty1[4];
    int lab[4] = {0, 0, 0, 0};
    if (active) {
        const float4* tbp = (const float4*)(tboxes + ((size_t)b * T + tt * 4) * 4);
        int4 lb = *(const int4*)(tlabels + (size_t)b * T + tt * 4);
        lab[0] = lb.x; lab[1] = lb.y; lab[2] = lb.z; lab[3] = lb.w;
        #pragma unroll
        for (int k = 0; k < 4; ++k) {
            float4 bx = tbp[k];
            Tx0[k] = bx.x - 0.5f * bx.z; Ty0[k] = bx.y - 0.5f * bx.w;
            Tx1[k] = bx.x + 0.5f * bx.z; Ty1[k] = bx.y + 0.5f * bx.w;
        }
    }

    __syncthreads();

    if (!active) return;

    const float* cls0 = s_cls + tq * C;  // + j*NTQ*C as imm offsets
    float* op = out + ((size_t)b * Q + q0 + tq) * T + tt * 4;

    #pragma unroll
    for (int j = 0; j < NQ; ++j) {
        float4 pB = s_pB[tq + NTQ * j];  // broadcast b128 (<=3 addrs/wave)
        float pw = pB.z - pB.x, ph = pB.w - pB.y;
        float pa = pw * ph;
        const float* clsj = cls0 + j * NTQ * C;

        float cls_k[4] = { clsj[lab[0]], clsj[lab[1]], clsj[lab[2]], clsj[lab[3]] };

        float4 res;
        #pragma unroll
        for (int k = 0; k < 4; ++k) {
            float dx0 = pB.x - Tx0[k], dx1 = pB.z - Tx1[k];
            float dy0 = pB.y - Ty0[k], dy1 = pB.w - Ty1[k];

            float tw = Tx1[k] - Tx0[k], th = Ty1[k] - Ty0[k];
            float ta = tw * th;

            float wi = fminf(pB.z, Tx1[k]) - fmaxf(pB.x, Tx0[k]);
            float hi = fminf(pB.w, Ty1[k]) - fmaxf(pB.y, Ty0[k]);
            float iw = fmaxf(wi, 0.0f), ih = fmaxf(hi, 0.0f);
            float inter = iw * ih;
            float uni = (pa + ta) - inter;
            float cw  = (pw + tw) - wi;      // max+min identity
            float ch  = (ph + th) - hi;
            float ca  = cw * ch;

            // cbbox from corner diffs: |dcx|=0.5|dx0+dx1|, |dw|=|dx1-dx0|
            float cb = fabsf(dx1 - dx0) + fabsf(dy1 - dy0);
            cb = fmaf(0.5f, fabsf(dx0 + dx1), cb);
            cb = fmaf(0.5f, fabsf(dy0 + dy1), cb);

            float num = fmaf(uni, uni, inter * ca);
            float r   = fast_rcp(uni * ca);
            float c   = fmaf(5.0f, cb, cls_k[k]);
            c = fmaf(num * r, -2.0f, c);

            if (c != c) c = 1.0f;            // nan_to_num; clamp provably no-op

            (&res.x)[k] = c;
        }
        *(float4*)(op + (size_t)(NTQ * j) * T) = res;   // coalesced 16B
    }
}

extern "C" void kernel_launch(void* const* d_in, const int* in_sizes, int n_in,
                              void* d_out, int out_size, void* d_ws, size_t ws_size,
                              hipStream_t stream) {
    const float* logits  = (const float*)d_in[0];  // [B,Q,C]
    const float* pboxes  = (const float*)d_in[1];  // [B,Q,4]
    const int*   tlabels = (const int*)  d_in[2];  // [B,T]
    const float* tboxes  = (const float*)d_in[3];  // [B,T,4]
    float* out = (float*)d_out;                    // [B,Q,T]

    dim3 grid(B * (Q / QTILE));   // 4800 blocks
    dim3 block(BLOCK);
    matcher_cost_kernel<<<grid, block, 0, stream>>>(logits, pboxes, tlabels, tboxes, out);
}

// Round 15
// 31.631 us; speedup vs baseline: 2.9958x; 1.0161x over previous
//
#include <hip/hip_runtime.h>

// HungarianMatcher batched cost matrix. B=64, Q=900, T=300, C=80.
// cost = 5*cbbox + (2*ccls + 2) - 2*(inter*ca + uni^2)/(uni*ca)
//
// R15: deep unroll (NQ=9, R12's proven ILP) AND a <=64-VGPR working set,
// reached NATURALLY (no min-waves clause -- R10/R13 proved it forces
// spill). Thread owns 2 t's (8 xyxy regs + 2 labs + 10 hoisted: tw,th,
// ta,tsx,tsy per t) x 9 q's (QTILE=18, NTQ=2, q=q0+tq+2j). Peak live
// ~50 regs -> 8 waves/SIMD ceiling (2x R12's class). float2 stores
// (8B/lane, coalescing sweet spot). cbbox via hoisted sums:
// cb = |pw-tw| + |ph-th| + 0.5(|psx-tsx| + |psy-tsy|).

constexpr int B = 64, Q = 900, T = 300, C = 80;
constexpr int QTILE = 18;            // 50 q-tiles -> grid 3200
constexpr int BLOCK = 320;           // 5 waves; 300 active (2x150)
constexpr int NTQ   = 2;             // q sub-lanes
constexpr int NQ    = QTILE / NTQ;   // 9 q per thread
constexpr float ALPHA = 0.25f;

__device__ __forceinline__ float fast_rcp(float x) {
    return __builtin_amdgcn_rcpf(x);
}

// 2*(pos-neg)+2 with one exp, one rcp, one log.
__device__ __forceinline__ float focal2(float x) {
    float t  = __expf(-x);
    float p  = fast_rcp(1.0f + t);
    float L  = __logf(1.0f + t);      // = -log(p)
    float xL = x + L;                 // = -log(1-p)
    float omp = t * p;                // 1-p
    float pos = ALPHA * omp * omp * L;
    float neg = (1.0f - ALPHA) * p * p * xL;
    return fmaf(2.0f, pos - neg, 2.0f);
}

__global__ __launch_bounds__(BLOCK) void matcher_cost_kernel(
    const float* __restrict__ logits,    // [B,Q,C]
    const float* __restrict__ pboxes,    // [B,Q,4] cxcywh
    const int*   __restrict__ tlabels,   // [B,T]
    const float* __restrict__ tboxes,    // [B,T,4] cxcywh
    float* __restrict__ out)             // [B,Q,T]
{
    __shared__ float  s_cls[QTILE * C];  // 5.76 KB
    __shared__ float4 s_pB[QTILE];       // x0,y0,x1,y1

    const int bid = blockIdx.x;
    const int b   = bid / (Q / QTILE);
    const int q0  = (bid % (Q / QTILE)) * QTILE;
    const int tid = threadIdx.x;

    // ---- pred boxes (xyxy only) ----
    if (tid < QTILE) {
        float4 bx = *(const float4*)(pboxes + ((size_t)b * Q + q0 + tid) * 4);
        s_pB[tid] = make_float4(bx.x - 0.5f * bx.z, bx.y - 0.5f * bx.w,
                                bx.x + 0.5f * bx.z, bx.y + 0.5f * bx.w);
    }
    // ---- focal class table: 1440 entries ----
    {
        const float* lg = logits + ((size_t)b * Q + q0) * C;
        for (int i = tid; i < QTILE * C; i += BLOCK)
            s_cls[i] = focal2(lg[i]);
    }

    // ---- this thread's 2 targets: global -> registers ----
    const int tq = tid / 150;            // 0..1 active
    const int tt = tid - tq * 150;       // 0..149
    const bool active = (tid < NTQ * 150);

    float Tx0[2], Ty0[2], Tx1[2], Ty1[2];
    float tw[2], th[2], ta[2], tsx[2], tsy[2];
    int lab[2] = {0, 0};
    if (active) {
        const float4* tbp = (const float4*)(tboxes + ((size_t)b * T + tt * 2) * 4);
        int2 lb = *(const int2*)(tlabels + (size_t)b * T + tt * 2);
        lab[0] = lb.x; lab[1] = lb.y;
        #pragma unroll
        for (int k = 0; k < 2; ++k) {
            float4 bx = tbp[k];
            Tx0[k] = bx.x - 0.5f * bx.z; Ty0[k] = bx.y - 0.5f * bx.w;
            Tx1[k] = bx.x + 0.5f * bx.z; Ty1[k] = bx.y + 0.5f * bx.w;
            tw[k]  = bx.z;  th[k] = bx.w;  ta[k] = bx.z * bx.w;
            tsx[k] = Tx0[k] + Tx1[k];      tsy[k] = Ty0[k] + Ty1[k];
        }
    }

    __syncthreads();

    if (!active) return;

    const float* cls0 = s_cls + tq * C;  // + j*NTQ*C as imm offsets
    float* op = out + ((size_t)b * Q + q0 + tq) * T + tt * 2;

    #pragma unroll
    for (int j = 0; j < NQ; ++j) {
        float4 pB = s_pB[tq + NTQ * j];  // broadcast b128 (<=2 addrs/wave)
        float pw  = pB.z - pB.x, ph = pB.w - pB.y;
        float pa  = pw * ph;
        float psx = pB.x + pB.z, psy = pB.y + pB.w;
        const float* clsj = cls0 + j * NTQ * C;

        float cls_k[2] = { clsj[lab[0]], clsj[lab[1]] };

        float2 res;
        #pragma unroll
        for (int k = 0; k < 2; ++k) {
            float wi = fminf(pB.z, Tx1[k]) - fmaxf(pB.x, Tx0[k]);
            float hi = fminf(pB.w, Ty1[k]) - fmaxf(pB.y, Ty0[k]);
            float iw = fmaxf(wi, 0.0f), ih = fmaxf(hi, 0.0f);
            float inter = iw * ih;
            float uni = (pa + ta[k]) - inter;
            float cw  = (pw + tw[k]) - wi;   // max+min identity
            float ch  = (ph + th[k]) - hi;
            float ca  = cw * ch;

            // cbbox from hoisted sums
            float cb = fabsf(pw - tw[k]) + fabsf(ph - th[k]);
            float cs = fabsf(psx - tsx[k]) + fabsf(psy - tsy[k]);
            cb = fmaf(0.5f, cs, cb);

            float num = fmaf(uni, uni, inter * ca);
            float r   = fast_rcp(uni * ca);
            float c   = fmaf(5.0f, cb, cls_k[k]);
            c = fmaf(num * r, -2.0f, c);

            if (c != c) c = 1.0f;            // nan_to_num; clamp provably no-op

            (&res.x)[k] = c;
        }
        *(float2*)(op + (size_t)(NTQ * j) * T) = res;   // coalesced 8B
    }
}

extern "C" void kernel_launch(void* const* d_in, const int* in_sizes, int n_in,
                              void* d_out, int out_size, void* d_ws, size_t ws_size,
                              hipStream_t stream) {
    const float* logits  = (const float*)d_in[0];  // [B,Q,C]
    const float* pboxes  = (const float*)d_in[1];  // [B,Q,4]
    const int*   tlabels = (const int*)  d_in[2];  // [B,T]
    const float* tboxes  = (const float*)d_in[3];  // [B,T,4]
    float* out = (float*)d_out;                    // [B,Q,T]

    dim3 grid(B * (Q / QTILE));   // 3200 blocks
    dim3 block(BLOCK);
    matcher_cost_kernel<<<grid, block, 0, stream>>>(logits, pboxes, tlabels, tboxes, out);
}